// Round 8
// baseline (229.593 us; speedup 1.0000x reference)
//
#include <hip/hip_runtime.h>
#include <hip/hip_bf16.h>

typedef short bf16x8 __attribute__((ext_vector_type(8)));
typedef float f32x4 __attribute__((ext_vector_type(4)));
typedef float f32x16 __attribute__((ext_vector_type(16)));

#define N_B 4
#define N_T 2048
#define N_D 1024
#define N_H 16
#define N_DH 64

// 0.125 * log2(e): folds attention scale + exp->exp2 conversion into Q proj
#define Q_SCALE 0.18033688011112042f

__device__ __forceinline__ unsigned short f2bf(float f) {
  union { float f; unsigned int u; } c; c.f = f;
  unsigned int u = c.u;
  return (unsigned short)((u + 0x7FFFu + ((u >> 16) & 1u)) >> 16);
}

__device__ __forceinline__ unsigned cvtpk_bf16(float lo, float hi) {
  unsigned r;
  asm("v_cvt_pk_bf16_f32 %0, %1, %2" : "=v"(r) : "v"(lo), "v"(hi));
  return r;
}

// async global->LDS, 16B per lane (dest linear: wave base + lane*16)
__device__ __forceinline__ void gll16(const unsigned short* g, unsigned short* l) {
  __builtin_amdgcn_global_load_lds(
      (const __attribute__((address_space(1))) unsigned int*)(const void*)g,
      (__attribute__((address_space(3))) unsigned int*)(void*)l, 16, 0, 0);
}

// --------------------------------------------------- cast fp32 -> bf16 (7 arrays)
__global__ void cast_all(const float* __restrict__ wq, const float* __restrict__ wk,
                         const float* __restrict__ wv, const float* __restrict__ wo,
                         const float* __restrict__ q, const float* __restrict__ k,
                         const float* __restrict__ v,
                         unsigned short* __restrict__ ws) {
  const int z = blockIdx.z;
  const float* srcs[7] = {wq, wk, wv, wo, q, k, v};
  const int size = (z < 4) ? (N_D * N_D) : (N_B * N_T * N_D);
  const size_t off = (z < 4) ? (size_t)z * (N_D * N_D)
                             : (size_t)4 * (N_D * N_D) + (size_t)(z - 4) * (N_B * N_T * N_D);
  const int i = (blockIdx.x * 256 + threadIdx.x) * 8;
  if (i >= size) return;
  const float* src = srcs[z];
  float4 a = *(const float4*)(src + i);
  float4 b = *(const float4*)(src + i + 4);
  bf16x8 p;
  p[0] = (short)f2bf(a.x); p[1] = (short)f2bf(a.y);
  p[2] = (short)f2bf(a.z); p[3] = (short)f2bf(a.w);
  p[4] = (short)f2bf(b.x); p[5] = (short)f2bf(b.y);
  p[6] = (short)f2bf(b.z); p[7] = (short)f2bf(b.w);
  *(bf16x8*)(ws + off + i) = p;
}

// --------------------------------------------------------- qkv projection GEMM
// y = x @ W.T, all bf16. BK=64, st-swizzled LDS, global_load_lds staging.
// q output: [B,H,T,DH] scaled by Q_SCALE ; k: [B,H,T,DH] ; v: TRANSPOSED [B,H,DH,T].
__launch_bounds__(256, 2)
__global__ void proj_qkv(const unsigned short* __restrict__ qb,
                         const unsigned short* __restrict__ kb,
                         const unsigned short* __restrict__ vb,
                         const unsigned short* __restrict__ wq,
                         const unsigned short* __restrict__ wk,
                         const unsigned short* __restrict__ wv,
                         unsigned short* __restrict__ qh,
                         unsigned short* __restrict__ kh,
                         unsigned short* __restrict__ vt) {
  const int z = blockIdx.z;
  const unsigned short* X = (z == 0) ? qb : (z == 1) ? kb : vb;
  const unsigned short* W = (z == 0) ? wq : (z == 1) ? wk : wv;
  unsigned short* O = (z == 0) ? qh : (z == 1) ? kh : vt;

  __shared__ unsigned short lds_a[128 * 64];
  __shared__ unsigned short lds_b[128 * 64];

  const int tid = threadIdx.x;
  const int wave = tid >> 6, lane = tid & 63;
  const int wm = wave >> 1, wn = wave & 1;
  const int lr = lane & 15, lg = lane >> 4;
  const int orig = blockIdx.y * 8 + blockIdx.x;
  const int swz = (orig & 7) * 64 + (orig >> 3);
  const int m0 = (swz >> 3) * 128, n0 = (swz & 7) * 128;
  const int sw = (lr & 7) << 4;

  f32x4 acc[4][4] = {};

  for (int k0 = 0; k0 < N_D; k0 += 64) {
    __syncthreads();
#pragma unroll
    for (int it = 0; it < 4; ++it) {
      int c = it * 256 + tid;
      int row = c >> 3;
      int sb = ((c & 7) * 16) ^ ((row & 7) << 4);
      gll16(&X[(size_t)(m0 + row) * N_D + k0 + (sb >> 1)], &lds_a[c * 8]);
      gll16(&W[(size_t)(n0 + row) * N_D + k0 + (sb >> 1)], &lds_b[c * 8]);
    }
    __syncthreads();

#pragma unroll
    for (int kk = 0; kk < 2; ++kk) {
      bf16x8 af[4], bfr[4];
      const int cb = (lg * 16 + kk * 64);
#pragma unroll
      for (int m = 0; m < 4; ++m)
        af[m] = *(bf16x8*)&lds_a[(wm * 64 + m * 16 + lr) * 64 + ((cb ^ sw) >> 1)];
#pragma unroll
      for (int n = 0; n < 4; ++n)
        bfr[n] = *(bf16x8*)&lds_b[(wn * 64 + n * 16 + lr) * 64 + ((cb ^ sw) >> 1)];
#pragma unroll
      for (int m = 0; m < 4; ++m)
#pragma unroll
        for (int n = 0; n < 4; ++n)
          acc[m][n] = __builtin_amdgcn_mfma_f32_16x16x32_bf16(af[m], bfr[n], acc[m][n], 0, 0, 0);
    }
  }

  const float osc = (z == 0) ? Q_SCALE : 1.0f;
#pragma unroll
  for (int m = 0; m < 4; ++m)
#pragma unroll
    for (int n = 0; n < 4; ++n)
#pragma unroll
      for (int r = 0; r < 4; ++r) {
        int row = m0 + wm * 64 + m * 16 + lg * 4 + r;   // token (b*T+t)
        int col = n0 + wn * 64 + n * 16 + lr;           // feature
        int b = row >> 11, t = row & (N_T - 1);
        int hh = col >> 6, dh = col & 63;
        unsigned short val = f2bf(acc[m][n][r] * osc);
        if (z < 2)
          O[(((size_t)(b * N_H + hh)) * N_T + t) * N_DH + dh] = val;
        else
          O[(((size_t)(b * N_H + hh)) * N_DH + dh) * N_T + t] = val;
      }
}

// ------------------------------------------------------ output projection GEMM
__launch_bounds__(256, 2)
__global__ void proj_out(const unsigned short* __restrict__ A,
                         const unsigned short* __restrict__ W,
                         float* __restrict__ out) {
  __shared__ unsigned short lds_a[128 * 64];
  __shared__ unsigned short lds_b[128 * 64];

  const int tid = threadIdx.x;
  const int wave = tid >> 6, lane = tid & 63;
  const int wm = wave >> 1, wn = wave & 1;
  const int lr = lane & 15, lg = lane >> 4;
  const int orig = blockIdx.y * 8 + blockIdx.x;
  const int swz = (orig & 7) * 64 + (orig >> 3);
  const int m0 = (swz >> 3) * 128, n0 = (swz & 7) * 128;
  const int sw = (lr & 7) << 4;

  f32x4 acc[4][4] = {};

  for (int k0 = 0; k0 < N_D; k0 += 64) {
    __syncthreads();
#pragma unroll
    for (int it = 0; it < 4; ++it) {
      int c = it * 256 + tid;
      int row = c >> 3;
      int sb = ((c & 7) * 16) ^ ((row & 7) << 4);
      gll16(&A[(size_t)(m0 + row) * N_D + k0 + (sb >> 1)], &lds_a[c * 8]);
      gll16(&W[(size_t)(n0 + row) * N_D + k0 + (sb >> 1)], &lds_b[c * 8]);
    }
    __syncthreads();

#pragma unroll
    for (int kk = 0; kk < 2; ++kk) {
      bf16x8 af[4], bfr[4];
      const int cb = (lg * 16 + kk * 64);
#pragma unroll
      for (int m = 0; m < 4; ++m)
        af[m] = *(bf16x8*)&lds_a[(wm * 64 + m * 16 + lr) * 64 + ((cb ^ sw) >> 1)];
#pragma unroll
      for (int n = 0; n < 4; ++n)
        bfr[n] = *(bf16x8*)&lds_b[(wn * 64 + n * 16 + lr) * 64 + ((cb ^ sw) >> 1)];
#pragma unroll
      for (int m = 0; m < 4; ++m)
#pragma unroll
        for (int n = 0; n < 4; ++n)
          acc[m][n] = __builtin_amdgcn_mfma_f32_16x16x32_bf16(af[m], bfr[n], acc[m][n], 0, 0, 0);
    }
  }

#pragma unroll
  for (int m = 0; m < 4; ++m)
#pragma unroll
    for (int n = 0; n < 4; ++n)
#pragma unroll
      for (int r = 0; r < 4; ++r) {
        int row = m0 + wm * 64 + m * 16 + lg * 4 + r;
        int col = n0 + wn * 64 + n * 16 + lr;
        out[(size_t)row * N_D + col] = acc[m][n][r];
      }
}

// ----------------------------------------------------------- flash attention
// Block = 64 q rows (2 waves x 32), one (b,h); q-tiles {bx, 31-bx} (balanced:
// every block stages exactly 33 64-key tiles). 1024 blocks -> 4-5/CU resident,
// independent (no inter-block sync) -> latency of one block's staging hides
// under another's compute. Per wave: swapped-QK mfma_32x32x16, lane-local
// softmax (defer-max THR=8, base-2), P->bf16 A-frags via v_cvt_pk + one
// shfl_xor(32); l as scalar lane accumulator. setprio(1) around MFMA clusters.
__launch_bounds__(128, 2)
__global__ void attn(const unsigned short* __restrict__ qh,
                     const unsigned short* __restrict__ kh,
                     const unsigned short* __restrict__ vt,
                     unsigned short* __restrict__ att) {
  __shared__ unsigned short k_lds[2][64 * 64];   // [key][d], XOR-swizzled
  __shared__ unsigned short v_lds[2][64 * 64];   // [d][key], XOR-swizzled

  const int tid = threadIdx.x;
  const int wave = tid >> 6, lane = tid & 63;
  const int l31 = lane & 31, hi = lane >> 5;
  const int bh = blockIdx.y;
  const size_t base = (size_t)bh * N_T * N_DH;
  const unsigned short* Q = qh + base;
  const unsigned short* K = kh + base;
  const unsigned short* V = vt + base;           // [DH][T]
  const int b = bh >> 4, h = bh & 15;
  const int swr = (l31 & 7) << 4;                // frag-read swizzle (bytes)

  auto stage = [&](int buf, int kb2) {
    const int kk0 = kb2 * 64;
#pragma unroll
    for (int it = 0; it < 4; ++it) {
      int c = it * 128 + tid;
      int row = c >> 3;
      int sb = ((c & 7) * 16) ^ ((row & 7) << 4);
      gll16(&K[(size_t)(kk0 + row) * N_DH + (sb >> 1)], &k_lds[buf][c * 8]);
      gll16(&V[(size_t)row * N_T + kk0 + (sb >> 1)], &v_lds[buf][c * 8]);
    }
  };

  for (int half = 0; half < 2; ++half) {
    const int qt = half ? (31 - (int)blockIdx.x) : (int)blockIdx.x;  // 64-row tile
    const int q0 = qt * 64;
    const int q0w = q0 + wave * 32;              // this wave's rows

    // Q frags (B-operand): lane holds Q[q0w+l31][i*16+hi*8 .. +7]
    bf16x8 qf[4];
#pragma unroll
    for (int i = 0; i < 4; ++i)
      qf[i] = *(const bf16x8*)&Q[(size_t)(q0w + l31) * N_DH + i * 16 + hi * 8];

    float m_r = -INFINITY, l_lane = 0.f;
    f32x16 o0 = {}, o1 = {};                     // dv 0-31 / 32-63

    const int nkb = qt + 1;                      // 64-key LDS tiles

    __syncthreads();                             // prev half fully consumed
    stage(0, 0);

    for (int kb = 0; kb < nkb; ++kb) {
      const int cur = kb & 1;
      __syncthreads();               // own vmcnt drained -> buf[cur] ready
      if (kb + 1 < nkb) stage(cur ^ 1, kb + 1);

      const unsigned short* kt_ = k_lds[cur];
      const unsigned short* vt_ = v_lds[cur];

#pragma unroll
      for (int ks = 0; ks < 2; ++ks) {
        const int kgb = kb * 64 + ks * 32;       // sub-block key base
        if (kgb > q0w + 31) continue;            // fully masked (wave-uniform)

        // S^T = K @ Q^T: lane holds S[key=(j&3)+8*(j>>2)+4*hi][q=l31]
        f32x16 s = {};
        __builtin_amdgcn_s_setprio(1);
#pragma unroll
        for (int i = 0; i < 4; ++i) {
          bf16x8 kf = *(const bf16x8*)&kt_[(ks * 32 + l31) * 64 +
                                           (((i * 32 + hi * 16) ^ swr) >> 1)];
          s = __builtin_amdgcn_mfma_f32_32x32x16_bf16(kf, qf[i], s, 0, 0, 0);
        }
        __builtin_amdgcn_s_setprio(0);

        // causal mask: only the diagonal sub-block
        if (kgb == q0w) {
#pragma unroll
          for (int j = 0; j < 16; ++j)
            if ((j & 3) + 8 * (j >> 2) + 4 * hi > l31) s[j] = -1e30f;
        }

        // lane-local max + cross-half; defer-max (THR=8, base-2 domain)
        float mx = s[0];
#pragma unroll
        for (int j = 1; j < 16; ++j) mx = fmaxf(mx, s[j]);
        mx = fmaxf(mx, __shfl_xor(mx, 32));
        if (__any(mx > m_r + 8.0f)) {
          float mn = fmaxf(m_r, mx);
          float al = exp2f(m_r - mn);
          m_r = mn;
          l_lane *= al;
#pragma unroll
          for (int j = 0; j < 16; ++j) {
            float aj = __shfl(al, (j & 3) + 8 * (j >> 2) + 4 * hi);
            o0[j] *= aj; o1[j] *= aj;
          }
        }

        // P = exp2(S - m); l accumulates over this lane's keys + cross-half
#pragma unroll
        for (int j = 0; j < 16; ++j) s[j] = exp2f(s[j] - m_r);
        float lsum = 0.f;
#pragma unroll
        for (int j = 0; j < 16; ++j) lsum += s[j];
        l_lane += lsum + __shfl_xor(lsum, 32);

        // P -> bf16 A-frags (keys kgb..kgb+31) via cvt_pk + cross-half exchange
        unsigned t01 = cvtpk_bf16(s[0], s[1]),   t45 = cvtpk_bf16(s[4], s[5]);
        unsigned t23 = cvtpk_bf16(s[2], s[3]),   t67 = cvtpk_bf16(s[6], s[7]);
        unsigned u01 = cvtpk_bf16(s[8], s[9]),   u45 = cvtpk_bf16(s[12], s[13]);
        unsigned u23 = cvtpk_bf16(s[10], s[11]), u67 = cvtpk_bf16(s[14], s[15]);
        unsigned x01 = __shfl_xor(t01, 32), x45 = __shfl_xor(t45, 32);
        unsigned x23 = __shfl_xor(t23, 32), x67 = __shfl_xor(t67, 32);
        unsigned y01 = __shfl_xor(u01, 32), y45 = __shfl_xor(u45, 32);
        unsigned y23 = __shfl_xor(u23, 32), y67 = __shfl_xor(u67, 32);
        union { unsigned u[4]; bf16x8 v; } pa0, pa1;
        pa0.u[0] = hi ? x45 : t01;  pa0.u[1] = hi ? x67 : t23;
        pa0.u[2] = hi ? t45 : x01;  pa0.u[3] = hi ? t67 : x23;
        pa1.u[0] = hi ? y45 : u01;  pa1.u[1] = hi ? y67 : u23;
        pa1.u[2] = hi ? u45 : y01;  pa1.u[3] = hi ? u67 : y23;

        // V^T frags from LDS: row = dv-half*32 + l31, cols = 16-key chunk
        const int c0 = ((ks * 64 + hi * 16) ^ swr) >> 1;        // kc = 2*ks
        const int c1 = ((ks * 64 + 32 + hi * 16) ^ swr) >> 1;   // kc = 2*ks+1
        bf16x8 v00 = *(const bf16x8*)&vt_[l31 * 64 + c0];
        bf16x8 v01 = *(const bf16x8*)&vt_[(32 + l31) * 64 + c0];
        bf16x8 v10 = *(const bf16x8*)&vt_[l31 * 64 + c1];
        bf16x8 v11 = *(const bf16x8*)&vt_[(32 + l31) * 64 + c1];

        __builtin_amdgcn_s_setprio(1);
        o0 = __builtin_amdgcn_mfma_f32_32x32x16_bf16(pa0.v, v00, o0, 0, 0, 0);
        o1 = __builtin_amdgcn_mfma_f32_32x32x16_bf16(pa0.v, v01, o1, 0, 0, 0);
        o0 = __builtin_amdgcn_mfma_f32_32x32x16_bf16(pa1.v, v10, o0, 0, 0, 0);
        o1 = __builtin_amdgcn_mfma_f32_32x32x16_bf16(pa1.v, v11, o1, 0, 0, 0);
        __builtin_amdgcn_s_setprio(0);
      }
    }

    // epilogue: att[b, t, h*64+dv]
#pragma unroll
    for (int j = 0; j < 16; ++j) {
      int ridx = (j & 3) + 8 * (j >> 2) + 4 * hi;
      float inv = 1.0f / __shfl(l_lane, ridx);
      int t = q0w + ridx;
      size_t rowb = ((size_t)(b * N_T + t)) * N_D + h * 64 + l31;
      att[rowb]      = f2bf(o0[j] * inv);
      att[rowb + 32] = f2bf(o1[j] * inv);
    }
  }
}

// ---------------------------------------------------------------------- launch
extern "C" void kernel_launch(void* const* d_in, const int* in_sizes, int n_in,
                              void* d_out, int out_size, void* d_ws, size_t ws_size,
                              hipStream_t stream) {
  (void)in_sizes; (void)n_in; (void)out_size; (void)ws_size;
  const float* q  = (const float*)d_in[0];
  const float* k  = (const float*)d_in[1];
  const float* v  = (const float*)d_in[2];
  const float* wq = (const float*)d_in[3];
  const float* wk = (const float*)d_in[4];
  const float* wv = (const float*)d_in[5];
  const float* wo = (const float*)d_in[6];
  float* out = (float*)d_out;

  unsigned short* ws = (unsigned short*)d_ws;
  const size_t W_ELEMS = (size_t)N_D * N_D;           // 1M
  const size_t T_ELEMS = (size_t)N_B * N_T * N_D;     // 8M
  unsigned short* wqb = ws;                 // 4 weights
  unsigned short* wkb = wqb + W_ELEMS;
  unsigned short* wvb = wkb + W_ELEMS;
  unsigned short* wob = wvb + W_ELEMS;
  unsigned short* qb  = wob + W_ELEMS;      // bf16 inputs
  unsigned short* kb  = qb + T_ELEMS;
  unsigned short* vb  = kb + T_ELEMS;
  unsigned short* qhb = vb + T_ELEMS;
  unsigned short* khb = qhb + T_ELEMS;
  unsigned short* vtb = khb + T_ELEMS;
  unsigned short* att = qb;                 // alias: qb dead after proj_qkv

  cast_all<<<dim3(4096, 1, 7), 256, 0, stream>>>(wq, wk, wv, wo, q, k, v, ws);
  proj_qkv<<<dim3(8, 64, 3), 256, 0, stream>>>(qb, kb, vb, wqb, wkb, wvb, qhb, khb, vtb);
  attn<<<dim3(16, N_B * N_H), 128, 0, stream>>>(qhb, khb, vtb, att);
  proj_out<<<dim3(8, 64), 256, 0, stream>>>(att, wob, out);
}

// Round 9
// 200.223 us; speedup vs baseline: 1.1467x; 1.1467x over previous
//
#include <hip/hip_runtime.h>
#include <hip/hip_bf16.h>

typedef short bf16x8 __attribute__((ext_vector_type(8)));
typedef float f32x4 __attribute__((ext_vector_type(4)));
typedef float f32x16 __attribute__((ext_vector_type(16)));

#define N_B 4
#define N_T 2048
#define N_D 1024
#define N_H 16
#define N_DH 64

// 0.125 * log2(e): folds attention scale + exp->exp2 conversion into Q proj
#define Q_SCALE 0.18033688011112042f

__device__ __forceinline__ unsigned short f2bf(float f) {
  union { float f; unsigned int u; } c; c.f = f;
  unsigned int u = c.u;
  return (unsigned short)((u + 0x7FFFu + ((u >> 16) & 1u)) >> 16);
}

__device__ __forceinline__ unsigned cvtpk_bf16(float lo, float hi) {
  unsigned r;
  asm("v_cvt_pk_bf16_f32 %0, %1, %2" : "=v"(r) : "v"(lo), "v"(hi));
  return r;
}

// async global->LDS, 16B per lane (dest linear: wave base + lane*16)
__device__ __forceinline__ void gll16(const unsigned short* g, unsigned short* l) {
  __builtin_amdgcn_global_load_lds(
      (const __attribute__((address_space(1))) unsigned int*)(const void*)g,
      (__attribute__((address_space(3))) unsigned int*)(void*)l, 16, 0, 0);
}
__device__ __forceinline__ void gll16f(const float* g, float* l) {
  __builtin_amdgcn_global_load_lds(
      (const __attribute__((address_space(1))) unsigned int*)(const void*)g,
      (__attribute__((address_space(3))) unsigned int*)(void*)l, 16, 0, 0);
}

// --------------------------------------------------- cast fp32 -> bf16 (weights)
__global__ void cast_w(const float* __restrict__ wq, const float* __restrict__ wk,
                       const float* __restrict__ wv, const float* __restrict__ wo,
                       unsigned short* __restrict__ ws) {
  const int z = blockIdx.z;
  const float* srcs[4] = {wq, wk, wv, wo};
  const float* src = srcs[z];
  unsigned short* d = ws + (size_t)z * (N_D * N_D);
  const int i = (blockIdx.x * 256 + threadIdx.x) * 8;
  float4 a = *(const float4*)(src + i);
  float4 b = *(const float4*)(src + i + 4);
  bf16x8 p;
  p[0] = (short)f2bf(a.x); p[1] = (short)f2bf(a.y);
  p[2] = (short)f2bf(a.z); p[3] = (short)f2bf(a.w);
  p[4] = (short)f2bf(b.x); p[5] = (short)f2bf(b.y);
  p[6] = (short)f2bf(b.z); p[7] = (short)f2bf(b.w);
  *(bf16x8*)(d + i) = p;
}

// --------------------------------------------------------- qkv projection GEMM
// y = x @ W.T. A is fp32 (original inputs), staged via global_load_lds into a
// swizzled fp32 LDS tile; converted to bf16 with v_cvt_pk at fragment read.
// B (weights) bf16. q output: [B,H,T,DH] scaled by Q_SCALE ; k: [B,H,T,DH] ;
// v: TRANSPOSED [B,H,DH,T].
__launch_bounds__(256, 2)
__global__ void proj_qkv(const float* __restrict__ qf32,
                         const float* __restrict__ kf32,
                         const float* __restrict__ vf32,
                         const unsigned short* __restrict__ wq,
                         const unsigned short* __restrict__ wk,
                         const unsigned short* __restrict__ wv,
                         unsigned short* __restrict__ qh,
                         unsigned short* __restrict__ kh,
                         unsigned short* __restrict__ vt) {
  const int z = blockIdx.z;
  const float* X = (z == 0) ? qf32 : (z == 1) ? kf32 : vf32;
  const unsigned short* W = (z == 0) ? wq : (z == 1) ? wk : wv;
  unsigned short* O = (z == 0) ? qh : (z == 1) ? kh : vt;

  __shared__ float lds_af[128 * 64];            // 32 KB, swizzled fp32 A tile
  __shared__ unsigned short lds_b[128 * 64];    // 16 KB, swizzled bf16 B tile

  const int tid = threadIdx.x;
  const int wave = tid >> 6, lane = tid & 63;
  const int wm = wave >> 1, wn = wave & 1;
  const int lr = lane & 15, lg = lane >> 4;
  const int orig = blockIdx.y * 8 + blockIdx.x;
  const int swz = (orig & 7) * 64 + (orig >> 3);
  const int m0 = (swz >> 3) * 128, n0 = (swz & 7) * 128;
  const int sw = (lr & 7) << 4;

  f32x4 acc[4][4] = {};

  for (int k0 = 0; k0 < N_D; k0 += 64) {
    __syncthreads();
    // stage A (fp32): 128 rows x 64 floats, 16B chunks, row-XOR-swizzled source
#pragma unroll
    for (int it = 0; it < 8; ++it) {
      int c = it * 256 + tid;
      int row = c >> 4;
      int sb = ((c & 15) * 16) ^ ((row & 7) << 4);   // bytes within 256B row
      gll16f(&X[(size_t)(m0 + row) * N_D + k0 + (sb >> 2)], &lds_af[c * 4]);
    }
    // stage B (bf16): 128 rows x 64 bf16
#pragma unroll
    for (int it = 0; it < 4; ++it) {
      int c = it * 256 + tid;
      int row = c >> 3;
      int sb = ((c & 7) * 16) ^ ((row & 7) << 4);    // bytes within 128B row
      gll16(&W[(size_t)(n0 + row) * N_D + k0 + (sb >> 1)], &lds_b[c * 8]);
    }
    __syncthreads();

#pragma unroll
    for (int kk = 0; kk < 2; ++kk) {
      bf16x8 af[4], bfr[4];
#pragma unroll
      for (int m = 0; m < 4; ++m) {
        const char* pbase = (const char*)&lds_af[(wm * 64 + m * 16 + lr) * 64];
        const int cb = (kk * 128 + lg * 32) ^ sw;    // byte col (row&7 == lr&7)
        float4 f0 = *(const float4*)(pbase + cb);
        float4 f1 = *(const float4*)(pbase + (cb ^ 16));
        union { unsigned u[4]; bf16x8 v; } pk;
        pk.u[0] = cvtpk_bf16(f0.x, f0.y); pk.u[1] = cvtpk_bf16(f0.z, f0.w);
        pk.u[2] = cvtpk_bf16(f1.x, f1.y); pk.u[3] = cvtpk_bf16(f1.z, f1.w);
        af[m] = pk.v;
      }
      const int cb2 = (lg * 16 + kk * 64);
#pragma unroll
      for (int n = 0; n < 4; ++n)
        bfr[n] = *(bf16x8*)&lds_b[(wn * 64 + n * 16 + lr) * 64 + ((cb2 ^ sw) >> 1)];
#pragma unroll
      for (int m = 0; m < 4; ++m)
#pragma unroll
        for (int n = 0; n < 4; ++n)
          acc[m][n] = __builtin_amdgcn_mfma_f32_16x16x32_bf16(af[m], bfr[n], acc[m][n], 0, 0, 0);
    }
  }

  const float osc = (z == 0) ? Q_SCALE : 1.0f;
#pragma unroll
  for (int m = 0; m < 4; ++m)
#pragma unroll
    for (int n = 0; n < 4; ++n)
#pragma unroll
      for (int r = 0; r < 4; ++r) {
        int row = m0 + wm * 64 + m * 16 + lg * 4 + r;   // token (b*T+t)
        int col = n0 + wn * 64 + n * 16 + lr;           // feature
        int b = row >> 11, t = row & (N_T - 1);
        int hh = col >> 6, dh = col & 63;
        unsigned short val = f2bf(acc[m][n][r] * osc);
        if (z < 2)
          O[(((size_t)(b * N_H + hh)) * N_T + t) * N_DH + dh] = val;
        else
          O[(((size_t)(b * N_H + hh)) * N_DH + dh) * N_T + t] = val;
      }
}

// ------------------------------------------------------ output projection GEMM
__launch_bounds__(256, 2)
__global__ void proj_out(const unsigned short* __restrict__ A,
                         const unsigned short* __restrict__ W,
                         float* __restrict__ out) {
  __shared__ unsigned short lds_a[128 * 64];
  __shared__ unsigned short lds_b[128 * 64];

  const int tid = threadIdx.x;
  const int wave = tid >> 6, lane = tid & 63;
  const int wm = wave >> 1, wn = wave & 1;
  const int lr = lane & 15, lg = lane >> 4;
  const int orig = blockIdx.y * 8 + blockIdx.x;
  const int swz = (orig & 7) * 64 + (orig >> 3);
  const int m0 = (swz >> 3) * 128, n0 = (swz & 7) * 128;
  const int sw = (lr & 7) << 4;

  f32x4 acc[4][4] = {};

  for (int k0 = 0; k0 < N_D; k0 += 64) {
    __syncthreads();
#pragma unroll
    for (int it = 0; it < 4; ++it) {
      int c = it * 256 + tid;
      int row = c >> 3;
      int sb = ((c & 7) * 16) ^ ((row & 7) << 4);
      gll16(&A[(size_t)(m0 + row) * N_D + k0 + (sb >> 1)], &lds_a[c * 8]);
      gll16(&W[(size_t)(n0 + row) * N_D + k0 + (sb >> 1)], &lds_b[c * 8]);
    }
    __syncthreads();

#pragma unroll
    for (int kk = 0; kk < 2; ++kk) {
      bf16x8 af[4], bfr[4];
      const int cb = (lg * 16 + kk * 64);
#pragma unroll
      for (int m = 0; m < 4; ++m)
        af[m] = *(bf16x8*)&lds_a[(wm * 64 + m * 16 + lr) * 64 + ((cb ^ sw) >> 1)];
#pragma unroll
      for (int n = 0; n < 4; ++n)
        bfr[n] = *(bf16x8*)&lds_b[(wn * 64 + n * 16 + lr) * 64 + ((cb ^ sw) >> 1)];
#pragma unroll
      for (int m = 0; m < 4; ++m)
#pragma unroll
        for (int n = 0; n < 4; ++n)
          acc[m][n] = __builtin_amdgcn_mfma_f32_16x16x32_bf16(af[m], bfr[n], acc[m][n], 0, 0, 0);
    }
  }

#pragma unroll
  for (int m = 0; m < 4; ++m)
#pragma unroll
    for (int n = 0; n < 4; ++n)
#pragma unroll
      for (int r = 0; r < 4; ++r) {
        int row = m0 + wm * 64 + m * 16 + lg * 4 + r;
        int col = n0 + wn * 64 + n * 16 + lr;
        out[(size_t)row * N_D + col] = acc[m][n][r];
      }
}

// ----------------------------------------------------------- flash attention
// r7 schedule (best measured): block = 128 q rows (4 waves x 32), one (b,h),
// q-tiles {bx, 15-bx} (balanced: 34 k-tiles/block), grid 8x64. K/V^T staged in
// double-buffered swizzled LDS via global_load_lds. Per wave: swapped-QK
// mfma_32x32x16, lane-local softmax (defer-max THR=8, base-2), P -> bf16
// A-frags via v_cvt_pk + one shfl_xor(32). l accumulated via mfma(P, ones)
// (moves row-sum to the idle MFMA pipe; lands in the o-register row layout).
__launch_bounds__(256, 2)
__global__ void attn(const unsigned short* __restrict__ qh,
                     const unsigned short* __restrict__ kh,
                     const unsigned short* __restrict__ vt,
                     unsigned short* __restrict__ att) {
  __shared__ unsigned short k_lds[2][64 * 64];   // [key][d], XOR-swizzled
  __shared__ unsigned short v_lds[2][64 * 64];   // [d][key], XOR-swizzled

  const int tid = threadIdx.x;
  const int wave = tid >> 6, lane = tid & 63;
  const int l31 = lane & 31, hi = lane >> 5;
  const int bh = blockIdx.y;
  const size_t base = (size_t)bh * N_T * N_DH;
  const unsigned short* Q = qh + base;
  const unsigned short* K = kh + base;
  const unsigned short* V = vt + base;           // [DH][T]
  const int b = bh >> 4, h = bh & 15;
  const int swr = (l31 & 7) << 4;                // frag-read swizzle (bytes)

  bf16x8 ones;
#pragma unroll
  for (int j = 0; j < 8; ++j) ones[j] = (short)0x3F80;   // 1.0 bf16

  auto stage = [&](int buf, int kb2) {
    const int kk0 = kb2 * 64;
#pragma unroll
    for (int it = 0; it < 2; ++it) {
      int c = it * 256 + tid;
      int row = c >> 3;
      int sb = ((c & 7) * 16) ^ ((row & 7) << 4);
      gll16(&K[(size_t)(kk0 + row) * N_DH + (sb >> 1)], &k_lds[buf][c * 8]);
      gll16(&V[(size_t)row * N_T + kk0 + (sb >> 1)], &v_lds[buf][c * 8]);
    }
  };

  for (int half = 0; half < 2; ++half) {
    const int qt = half ? (15 - (int)blockIdx.x) : (int)blockIdx.x;
    const int q0 = qt * 128;
    const int q0w = q0 + wave * 32;              // this wave's rows

    // Q frags (B-operand): lane holds Q[q0w+l31][i*16+hi*8 .. +7]
    bf16x8 qf[4];
#pragma unroll
    for (int i = 0; i < 4; ++i)
      qf[i] = *(const bf16x8*)&Q[(size_t)(q0w + l31) * N_DH + i * 16 + hi * 8];

    float m_r = -INFINITY;
    f32x16 l_acc = {};                           // row-sums, o-register layout
    f32x16 o0 = {}, o1 = {};                     // dv 0-31 / 32-63

    const int nkb = 2 * qt + 2;                  // 64-key LDS tiles

    __syncthreads();                             // prev half fully consumed
    stage(0, 0);

    for (int kb = 0; kb < nkb; ++kb) {
      const int cur = kb & 1;
      __syncthreads();               // own vmcnt drained -> buf[cur] ready
      if (kb + 1 < nkb) stage(cur ^ 1, kb + 1);

      const unsigned short* kt_ = k_lds[cur];
      const unsigned short* vt_ = v_lds[cur];

#pragma unroll
      for (int ks = 0; ks < 2; ++ks) {
        const int kgb = kb * 64 + ks * 32;       // sub-block key base
        if (kgb > q0w + 31) continue;            // fully masked (wave-uniform)

        // S^T = K @ Q^T: lane holds S[key=(j&3)+8*(j>>2)+4*hi][q=l31]
        f32x16 s = {};
        __builtin_amdgcn_s_setprio(1);
#pragma unroll
        for (int i = 0; i < 4; ++i) {
          bf16x8 kf = *(const bf16x8*)&kt_[(ks * 32 + l31) * 64 +
                                           (((i * 32 + hi * 16) ^ swr) >> 1)];
          s = __builtin_amdgcn_mfma_f32_32x32x16_bf16(kf, qf[i], s, 0, 0, 0);
        }
        __builtin_amdgcn_s_setprio(0);

        // causal mask: only the diagonal sub-block
        if (kgb == q0w) {
#pragma unroll
          for (int j = 0; j < 16; ++j)
            if ((j & 3) + 8 * (j >> 2) + 4 * hi > l31) s[j] = -1e30f;
        }

        // lane-local max + cross-half; defer-max (THR=8, base-2 domain)
        float mx = s[0];
#pragma unroll
        for (int j = 1; j < 16; ++j) mx = fmaxf(mx, s[j]);
        mx = fmaxf(mx, __shfl_xor(mx, 32));
        if (__any(mx > m_r + 8.0f)) {
          float mn = fmaxf(m_r, mx);
          float al = exp2f(m_r - mn);
          m_r = mn;
#pragma unroll
          for (int j = 0; j < 16; ++j) {
            float aj = __shfl(al, (j & 3) + 8 * (j >> 2) + 4 * hi);
            o0[j] *= aj; o1[j] *= aj; l_acc[j] *= aj;
          }
        }

        // P = exp2(S - m)
#pragma unroll
        for (int j = 0; j < 16; ++j) s[j] = exp2f(s[j] - m_r);

        // P -> bf16 A-frags (keys kgb..kgb+31) via cvt_pk + cross-half exchange
        unsigned t01 = cvtpk_bf16(s[0], s[1]),   t45 = cvtpk_bf16(s[4], s[5]);
        unsigned t23 = cvtpk_bf16(s[2], s[3]),   t67 = cvtpk_bf16(s[6], s[7]);
        unsigned u01 = cvtpk_bf16(s[8], s[9]),   u45 = cvtpk_bf16(s[12], s[13]);
        unsigned u23 = cvtpk_bf16(s[10], s[11]), u67 = cvtpk_bf16(s[14], s[15]);
        unsigned x01 = __shfl_xor(t01, 32), x45 = __shfl_xor(t45, 32);
        unsigned x23 = __shfl_xor(t23, 32), x67 = __shfl_xor(t67, 32);
        unsigned y01 = __shfl_xor(u01, 32), y45 = __shfl_xor(u45, 32);
        unsigned y23 = __shfl_xor(u23, 32), y67 = __shfl_xor(u67, 32);
        union { unsigned u[4]; bf16x8 v; } pa0, pa1;
        pa0.u[0] = hi ? x45 : t01;  pa0.u[1] = hi ? x67 : t23;
        pa0.u[2] = hi ? t45 : x01;  pa0.u[3] = hi ? t67 : x23;
        pa1.u[0] = hi ? y45 : u01;  pa1.u[1] = hi ? y67 : u23;
        pa1.u[2] = hi ? u45 : y01;  pa1.u[3] = hi ? u67 : y23;

        // V^T frags from LDS: row = dv-half*32 + l31, cols = 16-key chunk
        const int c0 = ((ks * 64 + hi * 16) ^ swr) >> 1;        // kc = 2*ks
        const int c1 = ((ks * 64 + 32 + hi * 16) ^ swr) >> 1;   // kc = 2*ks+1
        bf16x8 v00 = *(const bf16x8*)&vt_[l31 * 64 + c0];
        bf16x8 v01 = *(const bf16x8*)&vt_[(32 + l31) * 64 + c0];
        bf16x8 v10 = *(const bf16x8*)&vt_[l31 * 64 + c1];
        bf16x8 v11 = *(const bf16x8*)&vt_[(32 + l31) * 64 + c1];

        __builtin_amdgcn_s_setprio(1);
        o0 = __builtin_amdgcn_mfma_f32_32x32x16_bf16(pa0.v, v00, o0, 0, 0, 0);
        o1 = __builtin_amdgcn_mfma_f32_32x32x16_bf16(pa0.v, v01, o1, 0, 0, 0);
        o0 = __builtin_amdgcn_mfma_f32_32x32x16_bf16(pa1.v, v10, o0, 0, 0, 0);
        o1 = __builtin_amdgcn_mfma_f32_32x32x16_bf16(pa1.v, v11, o1, 0, 0, 0);
        l_acc = __builtin_amdgcn_mfma_f32_32x32x16_bf16(pa0.v, ones, l_acc, 0, 0, 0);
        l_acc = __builtin_amdgcn_mfma_f32_32x32x16_bf16(pa1.v, ones, l_acc, 0, 0, 0);
        __builtin_amdgcn_s_setprio(0);
      }
    }

    // epilogue: att[b, t, h*64+dv]
#pragma unroll
    for (int j = 0; j < 16; ++j) {
      float inv = 1.0f / l_acc[j];
      int t = q0w + (j & 3) + 8 * (j >> 2) + 4 * hi;
      size_t rowb = ((size_t)(b * N_T + t)) * N_D + h * 64 + l31;
      att[rowb]      = f2bf(o0[j] * inv);
      att[rowb + 32] = f2bf(o1[j] * inv);
    }
  }
}

// ---------------------------------------------------------------------- launch
extern "C" void kernel_launch(void* const* d_in, const int* in_sizes, int n_in,
                              void* d_out, int out_size, void* d_ws, size_t ws_size,
                              hipStream_t stream) {
  (void)in_sizes; (void)n_in; (void)out_size; (void)ws_size;
  const float* q  = (const float*)d_in[0];
  const float* k  = (const float*)d_in[1];
  const float* v  = (const float*)d_in[2];
  const float* wq = (const float*)d_in[3];
  const float* wk = (const float*)d_in[4];
  const float* wv = (const float*)d_in[5];
  const float* wo = (const float*)d_in[6];
  float* out = (float*)d_out;

  unsigned short* ws = (unsigned short*)d_ws;
  const size_t W_ELEMS = (size_t)N_D * N_D;           // 1M
  const size_t T_ELEMS = (size_t)N_B * N_T * N_D;     // 8M
  unsigned short* wqb = ws;                 // 4 weights (bf16)
  unsigned short* wkb = wqb + W_ELEMS;
  unsigned short* wvb = wkb + W_ELEMS;
  unsigned short* wob = wvb + W_ELEMS;
  unsigned short* qhb = wob + W_ELEMS;
  unsigned short* khb = qhb + T_ELEMS;
  unsigned short* vtb = khb + T_ELEMS;
  unsigned short* att = vtb + T_ELEMS;

  cast_w<<<dim3(512, 1, 4), 256, 0, stream>>>(wq, wk, wv, wo, ws);
  proj_qkv<<<dim3(8, 64, 3), 256, 0, stream>>>(q, k, v, wqb, wkb, wvb, qhb, khb, vtb);
  attn<<<dim3(8, N_B * N_H), 256, 0, stream>>>(qhb, khb, vtb, att);
  proj_out<<<dim3(8, 64), 256, 0, stream>>>(att, wob, out);
}